// Round 13
// baseline (744.163 us; speedup 1.0000x reference)
//
#include <hip/hip_runtime.h>
#include <hip/hip_bf16.h>

// Problem constants: B=128, T=512, V=50000, E=100, U=128, K=32
#define B_  128
#define T_  512
#define E_  100
#define U_  128
#define K_  32
#define G4  512   // 4*U
#define KP  128   // padded K for MFMA GEMM
#define LGRP 8    // lstm time-group size

typedef _Float16 h2_t __attribute__((ext_vector_type(2)));
typedef __fp16   h2raw_t __attribute__((ext_vector_type(2)));
typedef short    bf16x8 __attribute__((ext_vector_type(8)));
typedef float    f32x4  __attribute__((ext_vector_type(4)));

__device__ __forceinline__ h2_t pk2(float a, float b) {
    h2raw_t r = __builtin_amdgcn_cvt_pkrtz(a, b);
    union { h2raw_t r; h2_t h; } u; u.r = r; return u.h;
}
__device__ __forceinline__ int h2_as_int(h2_t v) { union { h2_t h; int i; } u; u.h = v; return u.i; }
__device__ __forceinline__ h2_t int_as_h2(int v) { union { h2_t h; int i; } u; u.i = v; return u.h; }

#if __has_builtin(__builtin_amdgcn_fdot2)
__device__ __forceinline__ float fdot2_f(h2_t a, h2_t b, float c) {
    return __builtin_amdgcn_fdot2(a, b, c, false);
}
#else
__device__ __forceinline__ float fdot2_f(h2_t a, h2_t b, float c) {
    return c + (float)a.x * (float)b.x + (float)a.y * (float)b.y;
}
#endif

#if __has_builtin(__builtin_amdgcn_rcpf)
__device__ __forceinline__ float rcp_f(float x) { return __builtin_amdgcn_rcpf(x); }
#else
__device__ __forceinline__ float rcp_f(float x) { return 1.f / x; }
#endif

__device__ __forceinline__ unsigned short bf16_bits(float v) {
    __hip_bfloat16 b = __float2bfloat16(v);
    union { __hip_bfloat16 b; unsigned short s; } u; u.b = b; return u.s;
}

// ---------------------------------------------------------------------------
// Kernel A0: pack Bb[n][k] (n-major, K padded to 128, bf16) from Wk_f|Wk_b.
// ---------------------------------------------------------------------------
__global__ __launch_bounds__(128) void pack_b_kernel(
    const float* __restrict__ Wk_f, const float* __restrict__ Wk_b,
    __hip_bfloat16* __restrict__ Bb)
{
    const int n = blockIdx.x;     // 0..1023
    const int k = threadIdx.x;    // 0..127
    float v = 0.f;
    if (k < E_) v = (n < 512) ? Wk_f[k * 512 + n] : Wk_b[k * 512 + (n - 512)];
    Bb[n * KP + k] = __float2bfloat16(v);
}

// ---------------------------------------------------------------------------
// Kernel A: xk via MFMA (R10 version: A staged once, 4 N-groups in-kernel).
// ---------------------------------------------------------------------------
__global__ __launch_bounds__(256, 2) void xk_mfma_kernel(
    const int* __restrict__ tokens, const float* __restrict__ emb,
    const __hip_bfloat16* __restrict__ Bb,
    const float* __restrict__ b_f, const float* __restrict__ b_b,
    __hip_bfloat16* __restrict__ xk_f, __hip_bfloat16* __restrict__ xk_b)
{
    const int r0   = blockIdx.x * 32;
    const int tid  = threadIdx.x;
    const int wv   = tid >> 6;
    const int lane = tid & 63;
    const int quad = lane >> 4;
    const int l16  = lane & 15;

    __shared__ __align__(16) float C_lds[32][268];          // 34.3 KB
    unsigned short* A_st = (unsigned short*)&C_lds[0][0];   // [32][136] alias

    for (int idx = tid; idx < 32 * 64; idx += 256) {
        int r = idx >> 6, kk = idx & 63;
        unsigned int w = 0;
        if (kk < 50) {
            float2 v = *(const float2*)(emb +
                (long long)tokens[r0 + r] * E_ + 2 * kk);
            w = ((unsigned int)bf16_bits(v.y) << 16) | bf16_bits(v.x);
        }
        *(unsigned int*)&A_st[r * 136 + 2 * kk] = w;
    }
    __syncthreads();

    bf16x8 af[2][4];
    #pragma unroll
    for (int mt = 0; mt < 2; ++mt)
        #pragma unroll
        for (int kc = 0; kc < 4; ++kc)
            af[mt][kc] = *(const bf16x8*)&A_st[(mt * 16 + l16) * 136 +
                                               kc * 32 + quad * 8];
    __syncthreads();

    const unsigned short* Bu = (const unsigned short*)Bb;

    for (int ng = 0; ng < 4; ++ng) {
        const int n0 = ng * 256;

        bf16x8 bfr[4][4];
        #pragma unroll
        for (int nt = 0; nt < 4; ++nt)
            #pragma unroll
            for (int kc = 0; kc < 4; ++kc)
                bfr[nt][kc] = *(const bf16x8*)(Bu +
                    (n0 + wv * 64 + nt * 16 + l16) * KP + kc * 32 + quad * 8);

        f32x4 acc[2][4];
        #pragma unroll
        for (int mt = 0; mt < 2; ++mt)
            #pragma unroll
            for (int nt = 0; nt < 4; ++nt)
                acc[mt][nt] = (f32x4){0.f, 0.f, 0.f, 0.f};

        #pragma unroll
        for (int mt = 0; mt < 2; ++mt)
            #pragma unroll
            for (int nt = 0; nt < 4; ++nt)
                #pragma unroll
                for (int kc = 0; kc < 4; ++kc)
                    acc[mt][nt] = __builtin_amdgcn_mfma_f32_16x16x32_bf16(
                        af[mt][kc], bfr[nt][kc], acc[mt][nt], 0, 0, 0);

        #pragma unroll
        for (int mt = 0; mt < 2; ++mt)
            #pragma unroll
            for (int nt = 0; nt < 4; ++nt)
                #pragma unroll
                for (int v = 0; v < 4; ++v)
                    C_lds[mt * 16 + quad * 4 + v][wv * 64 + nt * 16 + l16] =
                        acc[mt][nt][v];
        __syncthreads();

        const float* bias = (n0 < 512) ? b_f : b_b;
        __hip_bfloat16* outp = (n0 < 512) ? xk_f : xk_b;
        const int nbase = n0 & 511;
        for (int idx = tid; idx < 32 * 128; idx += 256) {
            int r = idx >> 7, cc = (idx & 127) * 2;
            float v0 = C_lds[r][cc]     + bias[nbase + cc];
            float v1 = C_lds[r][cc + 1] + bias[nbase + cc + 1];
            unsigned int w = ((unsigned int)bf16_bits(v1) << 16) | bf16_bits(v0);
            *(unsigned int*)(outp + (long long)(r0 + r) * G4 + nbase + cc) = w;
        }
        __syncthreads();
    }
}

// ---------------------------------------------------------------------------
// Kernel B: LSTM + fused em. 256 blocks = (dir,batch), 512 threads.
// Wave w owns q in [16w,16w+16); lane = (part,qi), part-slice u in [32p,+32).
// Phase 1: 4 broadcast ds_read_b128 (packed-f16 h pairs) + 64 dot2; butterfly
// shfl_xor(16/32) reduces the 4 parts IN-WAVE (no pl LDS, no extra barrier).
// Phase 2: every wave finalizes its own 16 units (4 part-lanes bitwise
// identical -> free); ONE barrier/step; hpl double-buffered. h goes to LDS
// hgrp (double-buffered); at group end 4 waves run the h@ck GEMV to em
// directly (em_kernel and h_buf eliminated).
// ---------------------------------------------------------------------------
__device__ __forceinline__ float sigmoid_f(float x) {
    return rcp_f(1.f + __expf(-x));
}
__device__ __forceinline__ float tanh_f(float x) {
    return 1.f - 2.f * rcp_f(__expf(2.f * x) + 1.f);
}

__global__ __launch_bounds__(512, 1) void lstm_kernel(
    const __hip_bfloat16* __restrict__ xk_f,
    const __hip_bfloat16* __restrict__ xk_b,
    const float* __restrict__ Wr_f, const float* __restrict__ Wr_b,
    const float* __restrict__ ck,
    float* __restrict__ em_f, float* __restrict__ em_b)
{
    const int bid  = blockIdx.x;
    const int dir  = bid >> 7;
    const int b    = bid & 127;
    const int tid  = threadIdx.x;
    const int w    = tid >> 6;       // wave 0..7 -> q-slice [16w,+16)
    const int lane = tid & 63;
    const int p    = lane >> 4;      // part: u-slice [32p, +32)
    const int qi   = lane & 15;
    const int q    = 16 * w + qi;    // column-unit 0..127

    const float* Wr = dir ? Wr_b : Wr_f;
    const __hip_bfloat16* xk = dir ? xk_b : xk_f;
    float* emo = dir ? em_b : em_f;

    // wp[g][j] packs Wr[32p+2j][g*128+q], Wr[32p+2j+1][g*128+q]
    h2_t wp[4][16];
    #pragma unroll
    for (int g = 0; g < 4; ++g)
        #pragma unroll
        for (int j = 0; j < 16; ++j)
            wp[g][j] = pk2(
                Wr[(32 * p + 2 * j)     * G4 + g * 128 + q],
                Wr[(32 * p + 2 * j + 1) * G4 + g * 128 + q]);

    __shared__ __align__(16) unsigned int hpl[2][64];  // packed f16 h pairs
    __shared__ float hgrp[2][LGRP][U_];                // 8 KB, dbuf by group
    __shared__ float ck_t[32 * 129];                   // 16.5 KB, transposed

    for (int idx = tid; idx < 32 * 128; idx += 512) {
        int k = idx >> 7, u = idx & 127;
        ck_t[k * 129 + u] = ck[(dir * 128 + u) * K_ + k];
    }
    if (tid < 64) hpl[0][tid] = 0;
    float c = 0.f;
    __syncthreads();

    const long long rowbase = (long long)b * T_;
    const __hip_bfloat16* xkq = xk + rowbase * G4 + q;

    float xk_cur[LGRP][4];
    #pragma unroll
    for (int d = 0; d < LGRP; ++d) {
        int t = dir ? (T_ - 1 - d) : d;
        #pragma unroll
        for (int g = 0; g < 4; ++g)
            xk_cur[d][g] = (p == 0)
                ? __bfloat162float(xkq[(long long)t * G4 + g * 128]) : 0.f;
    }

    for (int grp = 0; grp < T_ / LGRP; ++grp) {
        // clustered prefetch of next group's xk (part-0 lanes only)
        float xk_nxt[LGRP][4];
        #pragma unroll
        for (int d = 0; d < LGRP; ++d)
            #pragma unroll
            for (int g = 0; g < 4; ++g) xk_nxt[d][g] = 0.f;
        if (p == 0 && grp + 1 < T_ / LGRP) {
            #pragma unroll
            for (int d = 0; d < LGRP; ++d) {
                int s = (grp + 1) * LGRP + d;
                int t = dir ? (T_ - 1 - s) : s;
                #pragma unroll
                for (int g = 0; g < 4; ++g)
                    xk_nxt[d][g] =
                        __bfloat162float(xkq[(long long)t * G4 + g * 128]);
            }
        }

        #pragma unroll
        for (int d = 0; d < LGRP; ++d) {
            const int s   = grp * LGRP + d;
            const int buf = s & 1;

            // ---- phase 1: own-part partials, 4 gates ----
            float a0 = xk_cur[d][0];   // zero on p!=0 lanes
            float a1 = xk_cur[d][1];
            float a2 = xk_cur[d][2];
            float a3 = xk_cur[d][3];

            #pragma unroll
            for (int m = 0; m < 4; ++m) {
                uint4 hh4 = *(const uint4*)&hpl[buf][16 * p + 4 * m];
                unsigned int hw[4] = {hh4.x, hh4.y, hh4.z, hh4.w};
                #pragma unroll
                for (int jj = 0; jj < 4; ++jj) {
                    h2_t hh = int_as_h2((int)hw[jj]);
                    int j = 4 * m + jj;
                    a0 = fdot2_f(hh, wp[0][j], a0);
                    a1 = fdot2_f(hh, wp[1][j], a1);
                    a2 = fdot2_f(hh, wp[2][j], a2);
                    a3 = fdot2_f(hh, wp[3][j], a3);
                }
            }

            // ---- butterfly over parts (in-wave) ----
            a0 += __shfl_xor(a0, 16, 64);  a0 += __shfl_xor(a0, 32, 64);
            a1 += __shfl_xor(a1, 16, 64);  a1 += __shfl_xor(a1, 32, 64);
            a2 += __shfl_xor(a2, 16, 64);  a2 += __shfl_xor(a2, 32, 64);
            a3 += __shfl_xor(a3, 16, 64);  a3 += __shfl_xor(a3, 32, 64);

            // ---- phase 2: all lanes (4-way part-redundant, bitwise same) --
            c = sigmoid_f(a1) * c + sigmoid_f(a0) * tanh_f(a2);
            float h = sigmoid_f(a3) * tanh_f(c);

            if (p == 0) hgrp[grp & 1][d][q] = h;

            // pack next-step h pairs: lane j<8 -> (h@qi=2j, h@qi=2j+1)
            float hA = __shfl(h, 2 * (lane & 7), 64);
            float hB = __shfl(h, 2 * (lane & 7) + 1, 64);
            if (lane < 8)
                hpl[buf ^ 1][8 * w + lane] =
                    (unsigned int)h2_as_int(pk2(hA, hB));
            __syncthreads();             // the ONLY barrier per step
        }

        // ---- fused em GEMV for this group (4 waves; hgrp dbuf => no race) --
        if (tid < 256) {
            int d2 = tid >> 5, k = tid & 31;
            const float* hrow = &hgrp[grp & 1][d2][0];
            const float* crow = &ck_t[k * 129];
            float sum = 0.f;
            #pragma unroll 16
            for (int u = 0; u < 128; ++u)
                sum = fmaf(hrow[u], crow[u], sum);
            int s = grp * LGRP + d2;
            int t = dir ? (T_ - 1 - s) : s;
            emo[(rowbase + t) * K_ + k] = sum;
        }

        #pragma unroll
        for (int d = 0; d < LGRP; ++d)
            #pragma unroll
            for (int g = 0; g < 4; ++g) xk_cur[d][g] = xk_nxt[d][g];
    }
}

// ---------------------------------------------------------------------------
// Kernel D: CRF logZ. 128 blocks x 1 wave; em = em_f + em_b + cb.
// ---------------------------------------------------------------------------
#define PF_ 8
__global__ __launch_bounds__(64) void crf_kernel(
    const float* __restrict__ em_f, const float* __restrict__ em_b,
    const float* __restrict__ cb,
    const float* __restrict__ trans,
    float* __restrict__ out)
{
    const int b    = blockIdx.x;
    const int lane = threadIdx.x;
    const int k    = lane & 31;
    const int half = lane >> 5;

    float etr[16];
    #pragma unroll
    for (int i = 0; i < 16; ++i)
        etr[i] = __expf(trans[(half * 16 + i) * K_ + k]);

    const float cbk = cb[k];
    const long long base = (long long)b * T_ * K_;
    const float* ef = em_f + base;
    const float* eb = em_b + base;

    float ep[PF_];
    #pragma unroll
    for (int d = 0; d < PF_; ++d)
        ep[d] = ef[d * K_ + k] + eb[d * K_ + k] + cbk;

    float alpha = 0.f;
    for (int tb = 0; tb < T_; tb += PF_) {
        float en[PF_];
        if (tb + PF_ < T_) {
            #pragma unroll
            for (int d = 0; d < PF_; ++d) {
                int t = tb + PF_ + d;
                en[d] = ef[t * K_ + k] + eb[t * K_ + k] + cbk;
            }
        } else {
            #pragma unroll
            for (int d = 0; d < PF_; ++d) en[d] = 0.f;
        }

        #pragma unroll
        for (int d = 0; d < PF_; ++d) {
            const int t = tb + d;
            if (t == 0) {
                alpha = ep[d];
            } else {
                float M = __shfl(alpha, 0, 64);
                float pv = __expf(alpha - M);
                float acc = 0.f;
                #pragma unroll
                for (int i = 0; i < 16; ++i) {
                    float pw = __shfl(pv, half * 16 + i, 64);
                    acc = fmaf(pw, etr[i], acc);
                }
                acc += __shfl_xor(acc, 32, 64);
                alpha = M + __logf(acc) + ep[d];
            }
        }
        #pragma unroll
        for (int d = 0; d < PF_; ++d) ep[d] = en[d];
    }

    float m = alpha;
    #pragma unroll
    for (int d = 1; d < 32; d <<= 1)
        m = fmaxf(m, __shfl_xor(m, d, 64));
    float s = __expf(alpha - m);
    #pragma unroll
    for (int d = 1; d < 32; d <<= 1)
        s += __shfl_xor(s, d, 64);
    if (lane == 0) out[b] = m + __logf(s);
}

// ---------------------------------------------------------------------------
extern "C" void kernel_launch(void* const* d_in, const int* in_sizes, int n_in,
                              void* d_out, int out_size, void* d_ws, size_t ws_size,
                              hipStream_t stream)
{
    const int*   tokens = (const int*)  d_in[0];
    const float* emb    = (const float*)d_in[1];
    const float* Wk_f   = (const float*)d_in[2];
    const float* Wr_f   = (const float*)d_in[3];
    const float* b_f    = (const float*)d_in[4];
    const float* Wk_b   = (const float*)d_in[5];
    const float* Wr_b   = (const float*)d_in[6];
    const float* b_b    = (const float*)d_in[7];
    const float* ck     = (const float*)d_in[8];
    const float* cb     = (const float*)d_in[9];
    const float* trans  = (const float*)d_in[10];
    float* out = (float*)d_out;

    // ws: xk_f (67.1MB) | xk_b (67.1MB) | tail (33.6MB).
    // Tail holds: Bb (256KB, used pre-lstm) then em_f/em_b (8.4MB each,
    // written during lstm — Bb dead by then; safe by ordering).
    const long long ROWS = (long long)B_ * T_;     // 65536
    __hip_bfloat16* xk_f = (__hip_bfloat16*)d_ws;
    __hip_bfloat16* xk_b = xk_f + ROWS * G4;
    float* em_f = (float*)(xk_b + ROWS * G4);
    float* em_b = em_f + ROWS * K_;
    __hip_bfloat16* Bb = (__hip_bfloat16*)em_f;    // alias, safe by ordering

    hipLaunchKernelGGL(pack_b_kernel, dim3(1024), dim3(128), 0, stream,
                       Wk_f, Wk_b, Bb);
    hipLaunchKernelGGL(xk_mfma_kernel, dim3((int)(ROWS / 32)), dim3(256), 0,
                       stream, tokens, emb, Bb, b_f, b_b, xk_f, xk_b);
    hipLaunchKernelGGL(lstm_kernel, dim3(256), dim3(512), 0, stream,
                       xk_f, xk_b, Wr_f, Wr_b, ck, em_f, em_b);
    hipLaunchKernelGGL(crf_kernel, dim3(B_), dim3(64), 0, stream,
                       em_f, em_b, cb, trans, out);
}

// Round 14
// 691.314 us; speedup vs baseline: 1.0764x; 1.0764x over previous
//
#include <hip/hip_runtime.h>
#include <hip/hip_bf16.h>

// Problem constants: B=128, T=512, V=50000, E=100, U=128, K=32
#define B_  128
#define T_  512
#define E_  100
#define U_  128
#define K_  32
#define G4  512   // 4*U
#define KP  128   // padded K for MFMA GEMM
#define GRP 16    // lstm time-group size

typedef _Float16 h2_t __attribute__((ext_vector_type(2)));
typedef __fp16   h2raw_t __attribute__((ext_vector_type(2)));
typedef short    bf16x8 __attribute__((ext_vector_type(8)));
typedef float    f32x4  __attribute__((ext_vector_type(4)));

__device__ __forceinline__ h2_t pk2(float a, float b) {
    h2raw_t r = __builtin_amdgcn_cvt_pkrtz(a, b);
    union { h2raw_t r; h2_t h; } u; u.r = r; return u.h;
}
__device__ __forceinline__ int h2_as_int(h2_t v) { union { h2_t h; int i; } u; u.h = v; return u.i; }
__device__ __forceinline__ h2_t int_as_h2(int v) { union { h2_t h; int i; } u; u.i = v; return u.h; }

#if __has_builtin(__builtin_amdgcn_fdot2)
__device__ __forceinline__ float fdot2_f(h2_t a, h2_t b, float c) {
    return __builtin_amdgcn_fdot2(a, b, c, false);
}
#else
__device__ __forceinline__ float fdot2_f(h2_t a, h2_t b, float c) {
    return c + (float)a.x * (float)b.x + (float)a.y * (float)b.y;
}
#endif

#if __has_builtin(__builtin_amdgcn_rcpf)
__device__ __forceinline__ float rcp_f(float x) { return __builtin_amdgcn_rcpf(x); }
#else
__device__ __forceinline__ float rcp_f(float x) { return 1.f / x; }
#endif

__device__ __forceinline__ unsigned short bf16_bits(float v) {
    __hip_bfloat16 b = __float2bfloat16(v);
    union { __hip_bfloat16 b; unsigned short s; } u; u.b = b; return u.s;
}

// ---------------------------------------------------------------------------
// Kernel A0: pack Bb[n][k] (n-major, K padded to 128, bf16) from Wk_f|Wk_b.
// ---------------------------------------------------------------------------
__global__ __launch_bounds__(128) void pack_b_kernel(
    const float* __restrict__ Wk_f, const float* __restrict__ Wk_b,
    __hip_bfloat16* __restrict__ Bb)
{
    const int n = blockIdx.x;     // 0..1023
    const int k = threadIdx.x;    // 0..127
    float v = 0.f;
    if (k < E_) v = (n < 512) ? Wk_f[k * 512 + n] : Wk_b[k * 512 + (n - 512)];
    Bb[n * KP + k] = __float2bfloat16(v);
}

// ---------------------------------------------------------------------------
// Kernel A: xk via MFMA (R10 version: A staged once, 4 N-groups in-kernel).
// ---------------------------------------------------------------------------
__global__ __launch_bounds__(256, 2) void xk_mfma_kernel(
    const int* __restrict__ tokens, const float* __restrict__ emb,
    const __hip_bfloat16* __restrict__ Bb,
    const float* __restrict__ b_f, const float* __restrict__ b_b,
    __hip_bfloat16* __restrict__ xk_f, __hip_bfloat16* __restrict__ xk_b)
{
    const int r0   = blockIdx.x * 32;
    const int tid  = threadIdx.x;
    const int wv   = tid >> 6;
    const int lane = tid & 63;
    const int quad = lane >> 4;
    const int l16  = lane & 15;

    __shared__ __align__(16) float C_lds[32][268];          // 34.3 KB
    unsigned short* A_st = (unsigned short*)&C_lds[0][0];   // [32][136] alias

    for (int idx = tid; idx < 32 * 64; idx += 256) {
        int r = idx >> 6, kk = idx & 63;
        unsigned int w = 0;
        if (kk < 50) {
            float2 v = *(const float2*)(emb +
                (long long)tokens[r0 + r] * E_ + 2 * kk);
            w = ((unsigned int)bf16_bits(v.y) << 16) | bf16_bits(v.x);
        }
        *(unsigned int*)&A_st[r * 136 + 2 * kk] = w;
    }
    __syncthreads();

    bf16x8 af[2][4];
    #pragma unroll
    for (int mt = 0; mt < 2; ++mt)
        #pragma unroll
        for (int kc = 0; kc < 4; ++kc)
            af[mt][kc] = *(const bf16x8*)&A_st[(mt * 16 + l16) * 136 +
                                               kc * 32 + quad * 8];
    __syncthreads();

    const unsigned short* Bu = (const unsigned short*)Bb;

    for (int ng = 0; ng < 4; ++ng) {
        const int n0 = ng * 256;

        bf16x8 bfr[4][4];
        #pragma unroll
        for (int nt = 0; nt < 4; ++nt)
            #pragma unroll
            for (int kc = 0; kc < 4; ++kc)
                bfr[nt][kc] = *(const bf16x8*)(Bu +
                    (n0 + wv * 64 + nt * 16 + l16) * KP + kc * 32 + quad * 8);

        f32x4 acc[2][4];
        #pragma unroll
        for (int mt = 0; mt < 2; ++mt)
            #pragma unroll
            for (int nt = 0; nt < 4; ++nt)
                acc[mt][nt] = (f32x4){0.f, 0.f, 0.f, 0.f};

        #pragma unroll
        for (int mt = 0; mt < 2; ++mt)
            #pragma unroll
            for (int nt = 0; nt < 4; ++nt)
                #pragma unroll
                for (int kc = 0; kc < 4; ++kc)
                    acc[mt][nt] = __builtin_amdgcn_mfma_f32_16x16x32_bf16(
                        af[mt][kc], bfr[nt][kc], acc[mt][nt], 0, 0, 0);

        #pragma unroll
        for (int mt = 0; mt < 2; ++mt)
            #pragma unroll
            for (int nt = 0; nt < 4; ++nt)
                #pragma unroll
                for (int v = 0; v < 4; ++v)
                    C_lds[mt * 16 + quad * 4 + v][wv * 64 + nt * 16 + l16] =
                        acc[mt][nt][v];
        __syncthreads();

        const float* bias = (n0 < 512) ? b_f : b_b;
        __hip_bfloat16* outp = (n0 < 512) ? xk_f : xk_b;
        const int nbase = n0 & 511;
        for (int idx = tid; idx < 32 * 128; idx += 256) {
            int r = idx >> 7, cc = (idx & 127) * 2;
            float v0 = C_lds[r][cc]     + bias[nbase + cc];
            float v1 = C_lds[r][cc + 1] + bias[nbase + cc + 1];
            unsigned int w = ((unsigned int)bf16_bits(v1) << 16) | bf16_bits(v0);
            *(unsigned int*)(outp + (long long)(r0 + r) * G4 + nbase + cc) = w;
        }
        __syncthreads();
    }
}

// ---------------------------------------------------------------------------
// Kernel B: LSTM — exact R11 known-best (400 µs): R8 structure + rcp
// nonlinearity + GRP=16 clustered globals + packed-f16 h in LDS.
// ---------------------------------------------------------------------------
__device__ __forceinline__ float sigmoid_f(float x) {
    return rcp_f(1.f + __expf(-x));
}
__device__ __forceinline__ float tanh_f(float x) {
    return 1.f - 2.f * rcp_f(__expf(2.f * x) + 1.f);
}

__global__ __launch_bounds__(512, 1) void lstm_kernel(
    const __hip_bfloat16* __restrict__ xk_f,
    const __hip_bfloat16* __restrict__ xk_b,
    const float* __restrict__ Wr_f, const float* __restrict__ Wr_b,
    __hip_bfloat16* __restrict__ h_buf)
{
    const int bid  = blockIdx.x;
    const int dir  = bid >> 7;
    const int b    = bid & 127;
    const int tid  = threadIdx.x;
    const int part = tid >> 7;       // 0..3 : u-slice [32part, +32)
    const int q    = tid & 127;      // gate-column within each gate

    const float* Wr = dir ? Wr_b : Wr_f;
    const __hip_bfloat16* xk = dir ? xk_b : xk_f;

    h2_t wp[4][16];
    #pragma unroll
    for (int g = 0; g < 4; ++g)
        #pragma unroll
        for (int i = 0; i < 16; ++i)
            wp[g][i] = pk2(
                Wr[(part * 32 + 2 * i)     * G4 + g * 128 + q],
                Wr[(part * 32 + 2 * i + 1) * G4 + g * 128 + q]);

    __shared__ unsigned int hpl[64];               // packed f16 h pairs
    __shared__ __align__(16) float pl[4][U_][4];   // [gate][q][part-rotated]
    if (tid < 64) hpl[tid] = 0;
    float c = 0.f;
    __syncthreads();

    const int psw = (part + (q >> 3)) & 3;         // sum-invariant rotation
    const long long rowbase = (long long)b * T_;
    const __hip_bfloat16* xkp = xk + rowbase * G4 + tid;

    float xk_cur[GRP];
    #pragma unroll
    for (int d = 0; d < GRP; ++d) {
        int t = dir ? (T_ - 1 - d) : d;
        xk_cur[d] = __bfloat162float(xkp[t * G4]);
    }
    unsigned int hpack[GRP];
    #pragma unroll
    for (int d = 0; d < GRP; ++d) hpack[d] = 0;

    for (int g = 0; g < T_ / GRP; ++g) {
        float xk_nxt[GRP];
        #pragma unroll
        for (int d = 0; d < GRP; ++d) xk_nxt[d] = 0.f;
        if (g + 1 < T_ / GRP) {
            #pragma unroll
            for (int d = 0; d < GRP; ++d) {
                int s = (g + 1) * GRP + d;
                int t = dir ? (T_ - 1 - s) : s;
                xk_nxt[d] = __bfloat162float(xkp[t * G4]);
            }
        }

        #pragma unroll
        for (int d = 0; d < GRP; ++d) {
            float a0 = (part == 0) ? xk_cur[d] : 0.f;
            float a1 = (part == 1) ? xk_cur[d] : 0.f;
            float a2 = (part == 2) ? xk_cur[d] : 0.f;
            float a3 = (part == 3) ? xk_cur[d] : 0.f;

            int hpi = (int)hpl[part * 16 + (tid & 15)];

            #pragma unroll
            for (int i = 0; i < 16; ++i) {
                h2_t hh = int_as_h2(__builtin_amdgcn_readlane(hpi, i));
                a0 = fdot2_f(hh, wp[0][i], a0);
                a1 = fdot2_f(hh, wp[1][i], a1);
                a2 = fdot2_f(hh, wp[2][i], a2);
                a3 = fdot2_f(hh, wp[3][i], a3);
            }

            pl[0][q][psw] = a0;
            pl[1][q][psw] = a1;
            pl[2][q][psw] = a2;
            pl[3][q][psw] = a3;
            __syncthreads();

            if (tid < U_) {
                float4 v0 = *(const float4*)&pl[0][tid][0];
                float4 v1 = *(const float4*)&pl[1][tid][0];
                float4 v2 = *(const float4*)&pl[2][tid][0];
                float4 v3 = *(const float4*)&pl[3][tid][0];
                float zi = (v0.x + v0.y) + (v0.z + v0.w);
                float zf = (v1.x + v1.y) + (v1.z + v1.w);
                float zg = (v2.x + v2.y) + (v2.z + v2.w);
                float zo = (v3.x + v3.y) + (v3.z + v3.w);
                c = sigmoid_f(zf) * c + sigmoid_f(zi) * tanh_f(zg);
                float h = sigmoid_f(zo) * tanh_f(c);
                float hn = __shfl_down(h, 1, 64);
                if (!(tid & 1)) {
                    hpl[tid >> 1] = (unsigned int)h2_as_int(pk2(h, hn));
                    hpack[d] = ((unsigned int)bf16_bits(hn) << 16) | bf16_bits(h);
                }
            }
            __syncthreads();
        }

        if (tid < U_ && !(tid & 1)) {
            #pragma unroll
            for (int d = 0; d < GRP; ++d) {
                int s = g * GRP + d;
                int t = dir ? (T_ - 1 - s) : s;
                *(unsigned int*)(h_buf + (rowbase + t) * 256 + dir * U_ + tid) =
                    hpack[d];
            }
        }

        #pragma unroll
        for (int d = 0; d < GRP; ++d) xk_cur[d] = xk_nxt[d];
    }
}

// ---------------------------------------------------------------------------
// Kernel C: em = h_buf(65536x256 bf16) @ ck(256x32) + cb  -> f32 (65536x32).
// ---------------------------------------------------------------------------
__global__ __launch_bounds__(256) void em_kernel(
    const __hip_bfloat16* __restrict__ h_buf,
    const float* __restrict__ ck, const float* __restrict__ cb,
    float* __restrict__ em)
{
    const int tid  = threadIdx.x;
    const int part = tid >> 5;
    const int k    = tid & 31;

    float ckr[32];
    #pragma unroll
    for (int i = 0; i < 32; ++i)
        ckr[i] = ck[(part * 32 + i) * K_ + k];
    const float cbk = cb[k];

    __shared__ float h_l[8][256];
    __shared__ float part_l[8][8][K_];

    const int r0 = blockIdx.x * 64;

    for (int round = 0; round < 8; ++round) {
        const int rbase = r0 + round * 8;
        #pragma unroll
        for (int j = 0; j < 8; ++j)
            h_l[j][tid] = __bfloat162float(h_buf[(long long)(rbase + j) * 256 + tid]);
        __syncthreads();

        #pragma unroll
        for (int j = 0; j < 8; ++j) {
            float pp = 0.f;
            #pragma unroll
            for (int i = 0; i < 32; ++i)
                pp = fmaf(h_l[j][part * 32 + i], ckr[i], pp);
            part_l[j][part][k] = pp;
        }
        __syncthreads();

        {
            int j2 = tid >> 5;
            float e = cbk;
            #pragma unroll
            for (int pq = 0; pq < 8; ++pq) e += part_l[j2][pq][k];
            em[(long long)(rbase + j2) * K_ + k] = e;
        }
        __syncthreads();
    }
}

// ---------------------------------------------------------------------------
// Kernel D: CRF logZ — LINEAR-SPACE chain. w = exp(alpha - L) held directly;
// per step: 16 shfl*fma + xor-combine + multiply by prefetched exp(em).
// No exp/log/max on the serial chain. Renorm by w[0] once per 8 steps
// (growth <= e^63 < f32 max). Halves duplicate w (bitwise), sum over 32.
// ---------------------------------------------------------------------------
#define PF_ 8
__global__ __launch_bounds__(64) void crf_kernel(
    const float* __restrict__ em,
    const float* __restrict__ trans,
    float* __restrict__ out)
{
    const int b    = blockIdx.x;
    const int lane = threadIdx.x;
    const int k    = lane & 31;
    const int half = lane >> 5;

    float etr[16];
    #pragma unroll
    for (int i = 0; i < 16; ++i)
        etr[i] = __expf(trans[(half * 16 + i) * K_ + k]);

    const float* em_b = em + (long long)b * T_ * K_;

    float ep[PF_];
    #pragma unroll
    for (int d = 0; d < PF_; ++d)
        ep[d] = em_b[d * K_ + k];

    float w = 0.f;    // linear-space alpha, scaled
    float L = 0.f;    // accumulated log-scale
    for (int tb = 0; tb < T_; tb += PF_) {
        float en[PF_];
        if (tb + PF_ < T_) {
            #pragma unroll
            for (int d = 0; d < PF_; ++d)
                en[d] = em_b[(tb + PF_ + d) * K_ + k];
        } else {
            #pragma unroll
            for (int d = 0; d < PF_; ++d) en[d] = 0.f;
        }

        // off-chain: exp of emissions for this batch (lane-parallel)
        float eem[PF_];
        #pragma unroll
        for (int d = 0; d < PF_; ++d) eem[d] = __expf(ep[d]);

        #pragma unroll
        for (int d = 0; d < PF_; ++d) {
            if (tb + d == 0) {
                w = eem[d];                       // exp(em_0), L = 0
            } else {
                float acc = 0.f;
                #pragma unroll
                for (int i = 0; i < 16; ++i) {
                    float wv = __shfl(w, half * 16 + i, 64);
                    acc = fmaf(wv, etr[i], acc);
                }
                acc += __shfl_xor(acc, 32, 64);   // combine halves
                w = acc * eem[d];
            }
        }

        // renormalize once per batch: divide by w[k=0] (>0 always)
        {
            float w0 = __shfl(w, 0, 64);
            w *= rcp_f(w0);
            L += __logf(w0);
        }

        #pragma unroll
        for (int d = 0; d < PF_; ++d) ep[d] = en[d];
    }

    // logZ = L + log(sum_k w[k]); w duplicated across halves -> sum 32 lanes
    float s = w;
    #pragma unroll
    for (int d = 1; d < 32; d <<= 1)
        s += __shfl_xor(s, d, 64);
    if (lane == 0) out[b] = L + __logf(s);
}

// ---------------------------------------------------------------------------
extern "C" void kernel_launch(void* const* d_in, const int* in_sizes, int n_in,
                              void* d_out, int out_size, void* d_ws, size_t ws_size,
                              hipStream_t stream)
{
    const int*   tokens = (const int*)  d_in[0];
    const float* emb    = (const float*)d_in[1];
    const float* Wk_f   = (const float*)d_in[2];
    const float* Wr_f   = (const float*)d_in[3];
    const float* b_f    = (const float*)d_in[4];
    const float* Wk_b   = (const float*)d_in[5];
    const float* Wr_b   = (const float*)d_in[6];
    const float* b_b    = (const float*)d_in[7];
    const float* ck     = (const float*)d_in[8];
    const float* cb     = (const float*)d_in[9];
    const float* trans  = (const float*)d_in[10];
    float* out = (float*)d_out;

    const long long ROWS = (long long)B_ * T_;     // 65536
    __hip_bfloat16* xk_f  = (__hip_bfloat16*)d_ws;
    __hip_bfloat16* xk_b  = xk_f + ROWS * G4;
    __hip_bfloat16* h_buf = xk_b + ROWS * G4;
    __hip_bfloat16* Bb    = h_buf;                 // alias, safe by ordering
    float* em = (float*)d_ws;                      // alias, safe by ordering

    hipLaunchKernelGGL(pack_b_kernel, dim3(1024), dim3(128), 0, stream,
                       Wk_f, Wk_b, Bb);
    hipLaunchKernelGGL(xk_mfma_kernel, dim3((int)(ROWS / 32)), dim3(256), 0,
                       stream, tokens, emb, Bb, b_f, b_b, xk_f, xk_b);
    hipLaunchKernelGGL(lstm_kernel, dim3(256), dim3(512), 0, stream,
                       xk_f, xk_b, Wr_f, Wr_b, h_buf);
    hipLaunchKernelGGL(em_kernel, dim3((int)(ROWS / 64)), dim3(256), 0, stream,
                       h_buf, ck, cb, em);
    hipLaunchKernelGGL(crf_kernel, dim3(B_), dim3(64), 0, stream,
                       em, trans, out);
}

// Round 15
// 630.785 us; speedup vs baseline: 1.1797x; 1.0960x over previous
//
#include <hip/hip_runtime.h>
#include <hip/hip_bf16.h>

// Problem constants: B=128, T=512, V=50000, E=100, U=128, K=32
#define B_  128
#define T_  512
#define E_  100
#define U_  128
#define K_  32
#define G4  512   // 4*U
#define KP  128   // padded K for MFMA GEMM
#define GRP 8     // lstm time-group size

typedef _Float16 h2_t __attribute__((ext_vector_type(2)));
typedef _Float16 f16x8 __attribute__((ext_vector_type(8)));
typedef __fp16   h2raw_t __attribute__((ext_vector_type(2)));
typedef short    bf16x8 __attribute__((ext_vector_type(8)));
typedef float    f32x4  __attribute__((ext_vector_type(4)));

__device__ __forceinline__ h2_t pk2(float a, float b) {
    h2raw_t r = __builtin_amdgcn_cvt_pkrtz(a, b);
    union { h2raw_t r; h2_t h; } u; u.r = r; return u.h;
}
__device__ __forceinline__ int h2_as_int(h2_t v) { union { h2_t h; int i; } u; u.h = v; return u.i; }

#if __has_builtin(__builtin_amdgcn_rcpf)
__device__ __forceinline__ float rcp_f(float x) { return __builtin_amdgcn_rcpf(x); }
#else
__device__ __forceinline__ float rcp_f(float x) { return 1.f / x; }
#endif

__device__ __forceinline__ unsigned short bf16_bits(float v) {
    __hip_bfloat16 b = __float2bfloat16(v);
    union { __hip_bfloat16 b; unsigned short s; } u; u.b = b; return u.s;
}

// ---------------------------------------------------------------------------
// Kernel A0: pack Bb[n][k] (n-major, K padded to 128, bf16) from Wk_f|Wk_b.
// ---------------------------------------------------------------------------
__global__ __launch_bounds__(128) void pack_b_kernel(
    const float* __restrict__ Wk_f, const float* __restrict__ Wk_b,
    __hip_bfloat16* __restrict__ Bb)
{
    const int n = blockIdx.x;     // 0..1023
    const int k = threadIdx.x;    // 0..127
    float v = 0.f;
    if (k < E_) v = (n < 512) ? Wk_f[k * 512 + n] : Wk_b[k * 512 + (n - 512)];
    Bb[n * KP + k] = __float2bfloat16(v);
}

// ---------------------------------------------------------------------------
// Kernel A: xk via MFMA (R10 version: A staged once, 4 N-groups in-kernel).
// ---------------------------------------------------------------------------
__global__ __launch_bounds__(256, 2) void xk_mfma_kernel(
    const int* __restrict__ tokens, const float* __restrict__ emb,
    const __hip_bfloat16* __restrict__ Bb,
    const float* __restrict__ b_f, const float* __restrict__ b_b,
    __hip_bfloat16* __restrict__ xk_f, __hip_bfloat16* __restrict__ xk_b)
{
    const int r0   = blockIdx.x * 32;
    const int tid  = threadIdx.x;
    const int wv   = tid >> 6;
    const int lane = tid & 63;
    const int quad = lane >> 4;
    const int l16  = lane & 15;

    __shared__ __align__(16) float C_lds[32][268];          // 34.3 KB
    unsigned short* A_st = (unsigned short*)&C_lds[0][0];   // [32][136] alias

    for (int idx = tid; idx < 32 * 64; idx += 256) {
        int r = idx >> 6, kk = idx & 63;
        unsigned int w = 0;
        if (kk < 50) {
            float2 v = *(const float2*)(emb +
                (long long)tokens[r0 + r] * E_ + 2 * kk);
            w = ((unsigned int)bf16_bits(v.y) << 16) | bf16_bits(v.x);
        }
        *(unsigned int*)&A_st[r * 136 + 2 * kk] = w;
    }
    __syncthreads();

    bf16x8 af[2][4];
    #pragma unroll
    for (int mt = 0; mt < 2; ++mt)
        #pragma unroll
        for (int kc = 0; kc < 4; ++kc)
            af[mt][kc] = *(const bf16x8*)&A_st[(mt * 16 + l16) * 136 +
                                               kc * 32 + quad * 8];
    __syncthreads();

    const unsigned short* Bu = (const unsigned short*)Bb;

    for (int ng = 0; ng < 4; ++ng) {
        const int n0 = ng * 256;

        bf16x8 bfr[4][4];
        #pragma unroll
        for (int nt = 0; nt < 4; ++nt)
            #pragma unroll
            for (int kc = 0; kc < 4; ++kc)
                bfr[nt][kc] = *(const bf16x8*)(Bu +
                    (n0 + wv * 64 + nt * 16 + l16) * KP + kc * 32 + quad * 8);

        f32x4 acc[2][4];
        #pragma unroll
        for (int mt = 0; mt < 2; ++mt)
            #pragma unroll
            for (int nt = 0; nt < 4; ++nt)
                acc[mt][nt] = (f32x4){0.f, 0.f, 0.f, 0.f};

        #pragma unroll
        for (int mt = 0; mt < 2; ++mt)
            #pragma unroll
            for (int nt = 0; nt < 4; ++nt)
                #pragma unroll
                for (int kc = 0; kc < 4; ++kc)
                    acc[mt][nt] = __builtin_amdgcn_mfma_f32_16x16x32_bf16(
                        af[mt][kc], bfr[nt][kc], acc[mt][nt], 0, 0, 0);

        #pragma unroll
        for (int mt = 0; mt < 2; ++mt)
            #pragma unroll
            for (int nt = 0; nt < 4; ++nt)
                #pragma unroll
                for (int v = 0; v < 4; ++v)
                    C_lds[mt * 16 + quad * 4 + v][wv * 64 + nt * 16 + l16] =
                        acc[mt][nt][v];
        __syncthreads();

        const float* bias = (n0 < 512) ? b_f : b_b;
        __hip_bfloat16* outp = (n0 < 512) ? xk_f : xk_b;
        const int nbase = n0 & 511;
        for (int idx = tid; idx < 32 * 128; idx += 256) {
            int r = idx >> 7, cc = (idx & 127) * 2;
            float v0 = C_lds[r][cc]     + bias[nbase + cc];
            float v1 = C_lds[r][cc + 1] + bias[nbase + cc + 1];
            unsigned int w = ((unsigned int)bf16_bits(v1) << 16) | bf16_bits(v0);
            *(unsigned int*)(outp + (long long)(r0 + r) * G4 + nbase + cc) = w;
        }
        __syncthreads();
    }
}

// ---------------------------------------------------------------------------
// Kernel B: LSTM with MFMA recurrence. 256 blocks = (dir,batch), 512 thr.
// h (1x128) @ Wr (128x512) on the matrix pipe: A-frag = broadcast uint4 of
// packed-f16 hpl (A rows all = h, D rows identical); B = Wr f16 in registers
// (wave w owns cols [64w,+64) as 4 n-tiles x 4 k-chunks). 16 MFMA/wave/step.
// z extract: quad q emits tile q -> one coalesced b32 write/lane (zl[64w+lane]).
// Phase 2 (tid<128): z + xk (clustered per 8-step group), rcp nonlinearity,
// packed-h pairs to hpl + bf16 pairs buffered for clustered h_buf stores.
// ---------------------------------------------------------------------------
__device__ __forceinline__ float sigmoid_f(float x) {
    return rcp_f(1.f + __expf(-x));
}
__device__ __forceinline__ float tanh_f(float x) {
    return 1.f - 2.f * rcp_f(__expf(2.f * x) + 1.f);
}

__global__ __launch_bounds__(512, 1) void lstm_kernel(
    const __hip_bfloat16* __restrict__ xk_f,
    const __hip_bfloat16* __restrict__ xk_b,
    const float* __restrict__ Wr_f, const float* __restrict__ Wr_b,
    __hip_bfloat16* __restrict__ h_buf)
{
    const int bid  = blockIdx.x;
    const int dir  = bid >> 7;
    const int b    = bid & 127;
    const int tid  = threadIdx.x;
    const int w    = tid >> 6;       // wave 0..7 -> cols [64w, 64w+64)
    const int lane = tid & 63;
    const int quad = lane >> 4;
    const int l16  = lane & 15;

    const float* Wr = dir ? Wr_b : Wr_f;
    const __hip_bfloat16* xk = dir ? xk_b : xk_f;

    // B-frags: wb[tile][kc]; element j = Wr[kc*32+quad*8+j][64w+16*tile+l16]
    union uf16 { f16x8 v; h2_t p[4]; uint4 u; };
    f16x8 wb[4][4];
    #pragma unroll
    for (int tt = 0; tt < 4; ++tt) {
        const int col = 64 * w + 16 * tt + l16;
        #pragma unroll
        for (int kc = 0; kc < 4; ++kc) {
            const int k0 = kc * 32 + quad * 8;
            uf16 u;
            #pragma unroll
            for (int jj = 0; jj < 4; ++jj)
                u.p[jj] = pk2(Wr[(k0 + 2 * jj)     * G4 + col],
                              Wr[(k0 + 2 * jj + 1) * G4 + col]);
            wb[tt][kc] = u.v;
        }
    }

    __shared__ __align__(16) unsigned int hpl[64];  // packed f16 h pairs
    __shared__ float zl[G4];                        // z by gate-column
    if (tid < 64) hpl[tid] = 0;
    float c = 0.f;
    __syncthreads();

    const long long rowbase = (long long)b * T_;
    const __hip_bfloat16* xkq = xk + rowbase * G4 + tid;   // tid<128 lanes use

    float xk_cur[GRP][4];
    #pragma unroll
    for (int d = 0; d < GRP; ++d) {
        int t = dir ? (T_ - 1 - d) : d;
        #pragma unroll
        for (int g = 0; g < 4; ++g)
            xk_cur[d][g] = (tid < U_)
                ? __bfloat162float(xkq[(long long)t * G4 + g * 128]) : 0.f;
    }
    unsigned int hpack[GRP];
    #pragma unroll
    for (int d = 0; d < GRP; ++d) hpack[d] = 0;

    for (int g = 0; g < T_ / GRP; ++g) {
        // clustered prefetch of next group's xk (phase-2 lanes only)
        float xk_nxt[GRP][4];
        #pragma unroll
        for (int d = 0; d < GRP; ++d)
            #pragma unroll
            for (int gg = 0; gg < 4; ++gg) xk_nxt[d][gg] = 0.f;
        if (tid < U_ && g + 1 < T_ / GRP) {
            #pragma unroll
            for (int d = 0; d < GRP; ++d) {
                int s = (g + 1) * GRP + d;
                int t = dir ? (T_ - 1 - s) : s;
                #pragma unroll
                for (int gg = 0; gg < 4; ++gg)
                    xk_nxt[d][gg] =
                        __bfloat162float(xkq[(long long)t * G4 + gg * 128]);
            }
        }

        #pragma unroll
        for (int d = 0; d < GRP; ++d) {
            // ---- phase 1: MFMA recurrence ----
            uf16 afr[4];
            #pragma unroll
            for (int kc = 0; kc < 4; ++kc)
                afr[kc].u = *(const uint4*)&hpl[kc * 16 + quad * 4];

            f32x4 acc[4];
            #pragma unroll
            for (int tt = 0; tt < 4; ++tt)
                acc[tt] = (f32x4){0.f, 0.f, 0.f, 0.f};
            #pragma unroll
            for (int tt = 0; tt < 4; ++tt)
                #pragma unroll
                for (int kc = 0; kc < 4; ++kc)
                    acc[tt] = __builtin_amdgcn_mfma_f32_16x16x32_f16(
                        afr[kc].v, wb[tt][kc], acc[tt], 0, 0, 0);

            // D rows identical; quad q emits tile q -> coalesced write
            float zv = (quad == 0) ? acc[0][0]
                     : (quad == 1) ? acc[1][0]
                     : (quad == 2) ? acc[2][0] : acc[3][0];
            zl[64 * w + lane] = zv;
            __syncthreads();

            // ---- phase 2: 2 waves, 1 unit/lane ----
            if (tid < U_) {
                float zi = zl[tid]           + xk_cur[d][0];
                float zf = zl[U_ + tid]      + xk_cur[d][1];
                float zg = zl[2 * U_ + tid]  + xk_cur[d][2];
                float zo = zl[3 * U_ + tid]  + xk_cur[d][3];
                c = sigmoid_f(zf) * c + sigmoid_f(zi) * tanh_f(zg);
                float h = sigmoid_f(zo) * tanh_f(c);
                float hn = __shfl_down(h, 1, 64);
                if (!(tid & 1)) {
                    hpl[tid >> 1] = (unsigned int)h2_as_int(pk2(h, hn));
                    hpack[d] = ((unsigned int)bf16_bits(hn) << 16) | bf16_bits(h);
                }
            }
            __syncthreads();
        }

        // clustered h stores (even phase-2 lanes, 2 units each)
        if (tid < U_ && !(tid & 1)) {
            #pragma unroll
            for (int d = 0; d < GRP; ++d) {
                int s = g * GRP + d;
                int t = dir ? (T_ - 1 - s) : s;
                *(unsigned int*)(h_buf + (rowbase + t) * 256 + dir * U_ + tid) =
                    hpack[d];
            }
        }

        #pragma unroll
        for (int d = 0; d < GRP; ++d)
            #pragma unroll
            for (int gg = 0; gg < 4; ++gg) xk_cur[d][gg] = xk_nxt[d][gg];
    }
}

// ---------------------------------------------------------------------------
// Kernel C: em = h_buf(65536x256 bf16) @ ck(256x32) + cb  -> f32 (65536x32).
// ---------------------------------------------------------------------------
__global__ __launch_bounds__(256) void em_kernel(
    const __hip_bfloat16* __restrict__ h_buf,
    const float* __restrict__ ck, const float* __restrict__ cb,
    float* __restrict__ em)
{
    const int tid  = threadIdx.x;
    const int part = tid >> 5;
    const int k    = tid & 31;

    float ckr[32];
    #pragma unroll
    for (int i = 0; i < 32; ++i)
        ckr[i] = ck[(part * 32 + i) * K_ + k];
    const float cbk = cb[k];

    __shared__ float h_l[8][256];
    __shared__ float part_l[8][8][K_];

    const int r0 = blockIdx.x * 64;

    for (int round = 0; round < 8; ++round) {
        const int rbase = r0 + round * 8;
        #pragma unroll
        for (int j = 0; j < 8; ++j)
            h_l[j][tid] = __bfloat162float(h_buf[(long long)(rbase + j) * 256 + tid]);
        __syncthreads();

        #pragma unroll
        for (int j = 0; j < 8; ++j) {
            float pp = 0.f;
            #pragma unroll
            for (int i = 0; i < 32; ++i)
                pp = fmaf(h_l[j][part * 32 + i], ckr[i], pp);
            part_l[j][part][k] = pp;
        }
        __syncthreads();

        {
            int j2 = tid >> 5;
            float e = cbk;
            #pragma unroll
            for (int pq = 0; pq < 8; ++pq) e += part_l[j2][pq][k];
            em[(long long)(rbase + j2) * K_ + k] = e;
        }
        __syncthreads();
    }
}

// ---------------------------------------------------------------------------
// Kernel D: CRF logZ — linear-space chain (R13 version).
// ---------------------------------------------------------------------------
#define PF_ 8
__global__ __launch_bounds__(64) void crf_kernel(
    const float* __restrict__ em,
    const float* __restrict__ trans,
    float* __restrict__ out)
{
    const int b    = blockIdx.x;
    const int lane = threadIdx.x;
    const int k    = lane & 31;
    const int half = lane >> 5;

    float etr[16];
    #pragma unroll
    for (int i = 0; i < 16; ++i)
        etr[i] = __expf(trans[(half * 16 + i) * K_ + k]);

    const float* em_b = em + (long long)b * T_ * K_;

    float ep[PF_];
    #pragma unroll
    for (int d = 0; d < PF_; ++d)
        ep[d] = em_b[d * K_ + k];

    float w = 0.f;    // linear-space alpha, scaled
    float L = 0.f;    // accumulated log-scale
    for (int tb = 0; tb < T_; tb += PF_) {
        float en[PF_];
        if (tb + PF_ < T_) {
            #pragma unroll
            for (int d = 0; d < PF_; ++d)
                en[d] = em_b[(tb + PF_ + d) * K_ + k];
        } else {
            #pragma unroll
            for (int d = 0; d < PF_; ++d) en[d] = 0.f;
        }

        float eem[PF_];
        #pragma unroll
        for (int d = 0; d < PF_; ++d) eem[d] = __expf(ep[d]);

        #pragma unroll
        for (int d = 0; d < PF_; ++d) {
            if (tb + d == 0) {
                w = eem[d];
            } else {
                float acc = 0.f;
                #pragma unroll
                for (int i = 0; i < 16; ++i) {
                    float wv = __shfl(w, half * 16 + i, 64);
                    acc = fmaf(wv, etr[i], acc);
                }
                acc += __shfl_xor(acc, 32, 64);
                w = acc * eem[d];
            }
        }

        {
            float w0 = __shfl(w, 0, 64);
            w *= rcp_f(w0);
            L += __logf(w0);
        }

        #pragma unroll
        for (int d = 0; d < PF_; ++d) ep[d] = en[d];
    }

    float s = w;
    #pragma unroll
    for (int d = 1; d < 32; d <<= 1)
        s += __shfl_xor(s, d, 64);
    if (lane == 0) out[b] = L + __logf(s);
}

// ---------------------------------------------------------------------------
extern "C" void kernel_launch(void* const* d_in, const int* in_sizes, int n_in,
                              void* d_out, int out_size, void* d_ws, size_t ws_size,
                              hipStream_t stream)
{
    const int*   tokens = (const int*)  d_in[0];
    const float* emb    = (const float*)d_in[1];
    const float* Wk_f   = (const float*)d_in[2];
    const float* Wr_f   = (const float*)d_in[3];
    const float* b_f    = (const float*)d_in[4];
    const float* Wk_b   = (const float*)d_in[5];
    const float* Wr_b   = (const float*)d_in[6];
    const float* b_b    = (const float*)d_in[7];
    const float* ck     = (const float*)d_in[8];
    const float* cb     = (const float*)d_in[9];
    const float* trans  = (const float*)d_in[10];
    float* out = (float*)d_out;

    const long long ROWS = (long long)B_ * T_;     // 65536
    __hip_bfloat16* xk_f  = (__hip_bfloat16*)d_ws;
    __hip_bfloat16* xk_b  = xk_f + ROWS * G4;
    __hip_bfloat16* h_buf = xk_b + ROWS * G4;
    __hip_bfloat16* Bb    = h_buf;                 // alias, safe by ordering
    float* em = (float*)d_ws;                      // alias, safe by ordering

    hipLaunchKernelGGL(pack_b_kernel, dim3(1024), dim3(128), 0, stream,
                       Wk_f, Wk_b, Bb);
    hipLaunchKernelGGL(xk_mfma_kernel, dim3((int)(ROWS / 32)), dim3(256), 0,
                       stream, tokens, emb, Bb, b_f, b_b, xk_f, xk_b);
    hipLaunchKernelGGL(lstm_kernel, dim3(256), dim3(512), 0, stream,
                       xk_f, xk_b, Wr_f, Wr_b, h_buf);
    hipLaunchKernelGGL(em_kernel, dim3((int)(ROWS / 64)), dim3(256), 0, stream,
                       h_buf, ck, cb, em);
    hipLaunchKernelGGL(crf_kernel, dim3(B_), dim3(64), 0, stream,
                       em, trans, out);
}

// Round 16
// 627.240 us; speedup vs baseline: 1.1864x; 1.0057x over previous
//
#include <hip/hip_runtime.h>
#include <hip/hip_bf16.h>

// Problem constants: B=128, T=512, V=50000, E=100, U=128, K=32
#define B_  128
#define T_  512
#define V_  50000
#define VP  50016   // V padded to 32
#define E_  100
#define U_  128
#define K_  32
#define G4  512   // 4*U
#define KP  128   // padded K for MFMA GEMM
#define GRP 8     // lstm time-group size

typedef _Float16 h2_t __attribute__((ext_vector_type(2)));
typedef _Float16 f16x8 __attribute__((ext_vector_type(8)));
typedef __fp16   h2raw_t __attribute__((ext_vector_type(2)));
typedef short    bf16x8 __attribute__((ext_vector_type(8)));
typedef float    f32x4  __attribute__((ext_vector_type(4)));

__device__ __forceinline__ h2_t pk2(float a, float b) {
    h2raw_t r = __builtin_amdgcn_cvt_pkrtz(a, b);
    union { h2raw_t r; h2_t h; } u; u.r = r; return u.h;
}
__device__ __forceinline__ int h2_as_int(h2_t v) { union { h2_t h; int i; } u; u.h = v; return u.i; }

#if __has_builtin(__builtin_amdgcn_rcpf)
__device__ __forceinline__ float rcp_f(float x) { return __builtin_amdgcn_rcpf(x); }
#else
__device__ __forceinline__ float rcp_f(float x) { return 1.f / x; }
#endif

__device__ __forceinline__ unsigned short bf16_bits(float v) {
    __hip_bfloat16 b = __float2bfloat16(v);
    union { __hip_bfloat16 b; unsigned short s; } u; u.b = b; return u.s;
}

// ---------------------------------------------------------------------------
// Kernel A0: pack Bb[n][k] (n-major, K padded to 128, bf16) from Wk_f|Wk_b.
// ---------------------------------------------------------------------------
__global__ __launch_bounds__(128) void pack_b_kernel(
    const float* __restrict__ Wk_f, const float* __restrict__ Wk_b,
    __hip_bfloat16* __restrict__ Bb)
{
    const int n = blockIdx.x;     // 0..1023
    const int k = threadIdx.x;    // 0..127
    float v = 0.f;
    if (k < E_) v = (n < 512) ? Wk_f[k * 512 + n] : Wk_b[k * 512 + (n - 512)];
    Bb[n * KP + k] = __float2bfloat16(v);
}

// ---------------------------------------------------------------------------
// Kernel A: proj[v][1024] = emb[v] @ [Wk_f | Wk_b] + [b_f | b_b], bf16.
// Vocabulary-space GEMM (50016 rows): A-staging is SEQUENTIAL emb rows
// (coalesced, no token gather). Structure = R10 xk_mfma: A staged once,
// A-frags hoisted, 4 N-groups in-kernel; LDS epilogue; bias folded.
// ---------------------------------------------------------------------------
__global__ __launch_bounds__(256, 2) void proj_mfma_kernel(
    const float* __restrict__ emb,
    const __hip_bfloat16* __restrict__ Bb,
    const float* __restrict__ b_f, const float* __restrict__ b_b,
    __hip_bfloat16* __restrict__ proj)
{
    const int r0   = blockIdx.x * 32;
    const int tid  = threadIdx.x;
    const int wv   = tid >> 6;
    const int lane = tid & 63;
    const int quad = lane >> 4;
    const int l16  = lane & 15;

    __shared__ __align__(16) float C_lds[32][268];          // 34.3 KB
    unsigned short* A_st = (unsigned short*)&C_lds[0][0];   // [32][136] alias

    for (int idx = tid; idx < 32 * 64; idx += 256) {
        int r = idx >> 6, kk = idx & 63;
        int vr = r0 + r; if (vr >= V_) vr = V_ - 1;   // clamp: no OOB
        unsigned int w = 0;
        if (kk < 50) {
            float2 v = *(const float2*)(emb + (long long)vr * E_ + 2 * kk);
            w = ((unsigned int)bf16_bits(v.y) << 16) | bf16_bits(v.x);
        }
        *(unsigned int*)&A_st[r * 136 + 2 * kk] = w;
    }
    __syncthreads();

    bf16x8 af[2][4];
    #pragma unroll
    for (int mt = 0; mt < 2; ++mt)
        #pragma unroll
        for (int kc = 0; kc < 4; ++kc)
            af[mt][kc] = *(const bf16x8*)&A_st[(mt * 16 + l16) * 136 +
                                               kc * 32 + quad * 8];
    __syncthreads();

    const unsigned short* Bu = (const unsigned short*)Bb;

    for (int ng = 0; ng < 4; ++ng) {
        const int n0 = ng * 256;

        bf16x8 bfr[4][4];
        #pragma unroll
        for (int nt = 0; nt < 4; ++nt)
            #pragma unroll
            for (int kc = 0; kc < 4; ++kc)
                bfr[nt][kc] = *(const bf16x8*)(Bu +
                    (n0 + wv * 64 + nt * 16 + l16) * KP + kc * 32 + quad * 8);

        f32x4 acc[2][4];
        #pragma unroll
        for (int mt = 0; mt < 2; ++mt)
            #pragma unroll
            for (int nt = 0; nt < 4; ++nt)
                acc[mt][nt] = (f32x4){0.f, 0.f, 0.f, 0.f};

        #pragma unroll
        for (int mt = 0; mt < 2; ++mt)
            #pragma unroll
            for (int nt = 0; nt < 4; ++nt)
                #pragma unroll
                for (int kc = 0; kc < 4; ++kc)
                    acc[mt][nt] = __builtin_amdgcn_mfma_f32_16x16x32_bf16(
                        af[mt][kc], bfr[nt][kc], acc[mt][nt], 0, 0, 0);

        #pragma unroll
        for (int mt = 0; mt < 2; ++mt)
            #pragma unroll
            for (int nt = 0; nt < 4; ++nt)
                #pragma unroll
                for (int v = 0; v < 4; ++v)
                    C_lds[mt * 16 + quad * 4 + v][wv * 64 + nt * 16 + l16] =
                        acc[mt][nt][v];
        __syncthreads();

        const float* bias = (n0 < 512) ? b_f : b_b;
        const int nbase = n0 & 511;
        for (int idx = tid; idx < 32 * 128; idx += 256) {
            int r = idx >> 7, cc = (idx & 127) * 2;
            float v0 = C_lds[r][cc]     + bias[nbase + cc];
            float v1 = C_lds[r][cc + 1] + bias[nbase + cc + 1];
            unsigned int w = ((unsigned int)bf16_bits(v1) << 16) | bf16_bits(v0);
            *(unsigned int*)(proj + (long long)(r0 + r) * 1024 + n0 + cc) = w;
        }
        __syncthreads();
    }
}

// ---------------------------------------------------------------------------
// Kernel B: LSTM with MFMA recurrence (R14 known-best structure), gate
// inputs gathered straight from proj[token] (L3-resident). Tokens prefetched
// two groups ahead, proj rows one group ahead — off the serial chain.
// ---------------------------------------------------------------------------
__device__ __forceinline__ float sigmoid_f(float x) {
    return rcp_f(1.f + __expf(-x));
}
__device__ __forceinline__ float tanh_f(float x) {
    return 1.f - 2.f * rcp_f(__expf(2.f * x) + 1.f);
}

__global__ __launch_bounds__(512, 1) void lstm_kernel(
    const __hip_bfloat16* __restrict__ proj,
    const int* __restrict__ tokens,
    const float* __restrict__ Wr_f, const float* __restrict__ Wr_b,
    __hip_bfloat16* __restrict__ h_buf)
{
    const int bid  = blockIdx.x;
    const int dir  = bid >> 7;
    const int b    = bid & 127;
    const int tid  = threadIdx.x;
    const int w    = tid >> 6;       // wave 0..7 -> cols [64w, 64w+64)
    const int lane = tid & 63;
    const int quad = lane >> 4;
    const int l16  = lane & 15;

    const float* Wr = dir ? Wr_b : Wr_f;

    // B-frags: wb[tile][kc]; element j = Wr[kc*32+quad*8+j][64w+16*tile+l16]
    union uf16 { f16x8 v; h2_t p[4]; uint4 u; };
    f16x8 wb[4][4];
    #pragma unroll
    for (int tt = 0; tt < 4; ++tt) {
        const int col = 64 * w + 16 * tt + l16;
        #pragma unroll
        for (int kc = 0; kc < 4; ++kc) {
            const int k0 = kc * 32 + quad * 8;
            uf16 u;
            #pragma unroll
            for (int jj = 0; jj < 4; ++jj)
                u.p[jj] = pk2(Wr[(k0 + 2 * jj)     * G4 + col],
                              Wr[(k0 + 2 * jj + 1) * G4 + col]);
            wb[tt][kc] = u.v;
        }
    }

    __shared__ __align__(16) unsigned int hpl[64];  // packed f16 h pairs
    __shared__ float zl[G4];                        // z by gate-column
    if (tid < 64) hpl[tid] = 0;
    float c = 0.f;
    __syncthreads();

    const int tbase = b * T_;
    const long long rowbase = (long long)b * T_;
    // phase-2 lane gather base: proj + tok*1024 + dir*512 + tid (+ g*128)
    const __hip_bfloat16* pr = proj + dir * 512 + tid;

    // token pipeline: cur (group g), nxt (g+1)
    int tok_cur[GRP], tok_nxt[GRP];
    #pragma unroll
    for (int d = 0; d < GRP; ++d) {
        int t0 = dir ? (T_ - 1 - d) : d;
        tok_cur[d] = tokens[tbase + t0];
        int t1 = dir ? (T_ - 1 - (GRP + d)) : (GRP + d);
        tok_nxt[d] = tokens[tbase + t1];
    }

    float xk_cur[GRP][4];
    #pragma unroll
    for (int d = 0; d < GRP; ++d)
        #pragma unroll
        for (int g = 0; g < 4; ++g)
            xk_cur[d][g] = (tid < U_)
                ? __bfloat162float(pr[(long long)tok_cur[d] * 1024 + g * 128])
                : 0.f;

    unsigned int hpack[GRP];
    #pragma unroll
    for (int d = 0; d < GRP; ++d) hpack[d] = 0;

    for (int g = 0; g < T_ / GRP; ++g) {
        // clustered prefetch: proj rows for group g+1 (tokens already here)
        float xk_nxt[GRP][4];
        #pragma unroll
        for (int d = 0; d < GRP; ++d)
            #pragma unroll
            for (int gg = 0; gg < 4; ++gg) xk_nxt[d][gg] = 0.f;
        if (tid < U_ && g + 1 < T_ / GRP) {
            #pragma unroll
            for (int d = 0; d < GRP; ++d)
                #pragma unroll
                for (int gg = 0; gg < 4; ++gg)
                    xk_nxt[d][gg] = __bfloat162float(
                        pr[(long long)tok_nxt[d] * 1024 + gg * 128]);
        }
        // token prefetch for group g+2
        int tok_n2[GRP];
        #pragma unroll
        for (int d = 0; d < GRP; ++d) tok_n2[d] = 0;
        if (g + 2 < T_ / GRP) {
            #pragma unroll
            for (int d = 0; d < GRP; ++d) {
                int s = (g + 2) * GRP + d;
                int t = dir ? (T_ - 1 - s) : s;
                tok_n2[d] = tokens[tbase + t];
            }
        }

        #pragma unroll
        for (int d = 0; d < GRP; ++d) {
            // ---- phase 1: MFMA recurrence ----
            uf16 afr[4];
            #pragma unroll
            for (int kc = 0; kc < 4; ++kc)
                afr[kc].u = *(const uint4*)&hpl[kc * 16 + quad * 4];

            f32x4 acc[4];
            #pragma unroll
            for (int tt = 0; tt < 4; ++tt)
                acc[tt] = (f32x4){0.f, 0.f, 0.f, 0.f};
            #pragma unroll
            for (int tt = 0; tt < 4; ++tt)
                #pragma unroll
                for (int kc = 0; kc < 4; ++kc)
                    acc[tt] = __builtin_amdgcn_mfma_f32_16x16x32_f16(
                        afr[kc].v, wb[tt][kc], acc[tt], 0, 0, 0);

            float zv = (quad == 0) ? acc[0][0]
                     : (quad == 1) ? acc[1][0]
                     : (quad == 2) ? acc[2][0] : acc[3][0];
            zl[64 * w + lane] = zv;
            __syncthreads();

            // ---- phase 2: 2 waves, 1 unit/lane ----
            if (tid < U_) {
                float zi = zl[tid]           + xk_cur[d][0];
                float zf = zl[U_ + tid]      + xk_cur[d][1];
                float zg = zl[2 * U_ + tid]  + xk_cur[d][2];
                float zo = zl[3 * U_ + tid]  + xk_cur[d][3];
                c = sigmoid_f(zf) * c + sigmoid_f(zi) * tanh_f(zg);
                float h = sigmoid_f(zo) * tanh_f(c);
                float hn = __shfl_down(h, 1, 64);
                if (!(tid & 1)) {
                    hpl[tid >> 1] = (unsigned int)h2_as_int(pk2(h, hn));
                    hpack[d] = ((unsigned int)bf16_bits(hn) << 16) | bf16_bits(h);
                }
            }
            __syncthreads();
        }

        // clustered h stores (even phase-2 lanes, 2 units each)
        if (tid < U_ && !(tid & 1)) {
            #pragma unroll
            for (int d = 0; d < GRP; ++d) {
                int s = g * GRP + d;
                int t = dir ? (T_ - 1 - s) : s;
                *(unsigned int*)(h_buf + (rowbase + t) * 256 + dir * U_ + tid) =
                    hpack[d];
            }
        }

        #pragma unroll
        for (int d = 0; d < GRP; ++d) {
            #pragma unroll
            for (int gg = 0; gg < 4; ++gg) xk_cur[d][gg] = xk_nxt[d][gg];
            tok_nxt[d] = tok_n2[d];
        }
    }
}

// ---------------------------------------------------------------------------
// Kernel C: em = h_buf(65536x256 bf16) @ ck(256x32) + cb  -> f32 (65536x32).
// ---------------------------------------------------------------------------
__global__ __launch_bounds__(256) void em_kernel(
    const __hip_bfloat16* __restrict__ h_buf,
    const float* __restrict__ ck, const float* __restrict__ cb,
    float* __restrict__ em)
{
    const int tid  = threadIdx.x;
    const int part = tid >> 5;
    const int k    = tid & 31;

    float ckr[32];
    #pragma unroll
    for (int i = 0; i < 32; ++i)
        ckr[i] = ck[(part * 32 + i) * K_ + k];
    const float cbk = cb[k];

    __shared__ float h_l[8][256];
    __shared__ float part_l[8][8][K_];

    const int r0 = blockIdx.x * 64;

    for (int round = 0; round < 8; ++round) {
        const int rbase = r0 + round * 8;
        #pragma unroll
        for (int j = 0; j < 8; ++j)
            h_l[j][tid] = __bfloat162float(h_buf[(long long)(rbase + j) * 256 + tid]);
        __syncthreads();

        #pragma unroll
        for (int j = 0; j < 8; ++j) {
            float pp = 0.f;
            #pragma unroll
            for (int i = 0; i < 32; ++i)
                pp = fmaf(h_l[j][part * 32 + i], ckr[i], pp);
            part_l[j][part][k] = pp;
        }
        __syncthreads();

        {
            int j2 = tid >> 5;
            float e = cbk;
            #pragma unroll
            for (int pq = 0; pq < 8; ++pq) e += part_l[j2][pq][k];
            em[(long long)(rbase + j2) * K_ + k] = e;
        }
        __syncthreads();
    }
}

// ---------------------------------------------------------------------------
// Kernel D: CRF logZ — linear-space chain (R13 version).
// ---------------------------------------------------------------------------
#define PF_ 8
__global__ __launch_bounds__(64) void crf_kernel(
    const float* __restrict__ em,
    const float* __restrict__ trans,
    float* __restrict__ out)
{
    const int b    = blockIdx.x;
    const int lane = threadIdx.x;
    const int k    = lane & 31;
    const int half = lane >> 5;

    float etr[16];
    #pragma unroll
    for (int i = 0; i < 16; ++i)
        etr[i] = __expf(trans[(half * 16 + i) * K_ + k]);

    const float* em_b = em + (long long)b * T_ * K_;

    float ep[PF_];
    #pragma unroll
    for (int d = 0; d < PF_; ++d)
        ep[d] = em_b[d * K_ + k];

    float w = 0.f;    // linear-space alpha, scaled
    float L = 0.f;    // accumulated log-scale
    for (int tb = 0; tb < T_; tb += PF_) {
        float en[PF_];
        if (tb + PF_ < T_) {
            #pragma unroll
            for (int d = 0; d < PF_; ++d)
                en[d] = em_b[(tb + PF_ + d) * K_ + k];
        } else {
            #pragma unroll
            for (int d = 0; d < PF_; ++d) en[d] = 0.f;
        }

        float eem[PF_];
        #pragma unroll
        for (int d = 0; d < PF_; ++d) eem[d] = __expf(ep[d]);

        #pragma unroll
        for (int d = 0; d < PF_; ++d) {
            if (tb + d == 0) {
                w = eem[d];
            } else {
                float acc = 0.f;
                #pragma unroll
                for (int i = 0; i < 16; ++i) {
                    float wv = __shfl(w, half * 16 + i, 64);
                    acc = fmaf(wv, etr[i], acc);
                }
                acc += __shfl_xor(acc, 32, 64);
                w = acc * eem[d];
            }
        }

        {
            float w0 = __shfl(w, 0, 64);
            w *= rcp_f(w0);
            L += __logf(w0);
        }

        #pragma unroll
        for (int d = 0; d < PF_; ++d) ep[d] = en[d];
    }

    float s = w;
    #pragma unroll
    for (int d = 1; d < 32; d <<= 1)
        s += __shfl_xor(s, d, 64);
    if (lane == 0) out[b] = L + __logf(s);
}

// ---------------------------------------------------------------------------
extern "C" void kernel_launch(void* const* d_in, const int* in_sizes, int n_in,
                              void* d_out, int out_size, void* d_ws, size_t ws_size,
                              hipStream_t stream)
{
    const int*   tokens = (const int*)  d_in[0];
    const float* emb    = (const float*)d_in[1];
    const float* Wk_f   = (const float*)d_in[2];
    const float* Wr_f   = (const float*)d_in[3];
    const float* b_f    = (const float*)d_in[4];
    const float* Wk_b   = (const float*)d_in[5];
    const float* Wr_b   = (const float*)d_in[6];
    const float* b_b    = (const float*)d_in[7];
    const float* ck     = (const float*)d_in[8];
    const float* cb     = (const float*)d_in[9];
    const float* trans  = (const float*)d_in[10];
    float* out = (float*)d_out;

    // ws layout: proj (VP*1024 bf16 = 102.4MB) | h_buf (33.6MB) |
    //            em (8.4MB f32) | Bb (256KB bf16).  Total ~144.7MB.
    const long long ROWS = (long long)B_ * T_;     // 65536
    __hip_bfloat16* proj  = (__hip_bfloat16*)d_ws;
    __hip_bfloat16* h_buf = proj + (long long)VP * 1024;
    float* em = (float*)(h_buf + ROWS * 256);
    __hip_bfloat16* Bb = (__hip_bfloat16*)(em + ROWS * K_);

    hipLaunchKernelGGL(pack_b_kernel, dim3(1024), dim3(128), 0, stream,
                       Wk_f, Wk_b, Bb);
    hipLaunchKernelGGL(proj_mfma_kernel, dim3(VP / 32), dim3(256), 0, stream,
                       emb, Bb, b_f, b_b, proj);
    hipLaunchKernelGGL(lstm_kernel, dim3(256), dim3(512), 0, stream,
                       proj, tokens, Wr_f, Wr_b, h_buf);
    hipLaunchKernelGGL(em_kernel, dim3((int)(ROWS / 64)), dim3(256), 0, stream,
                       h_buf, ck, cb, em);
    hipLaunchKernelGGL(crf_kernel, dim3(B_), dim3(64), 0, stream,
                       em, trans, out);
}